// Round 11
// baseline (190.387 us; speedup 1.0000x reference)
//
#include <hip/hip_runtime.h>
#include <hip/hip_fp16.h>
#include <math.h>
#include <stdint.h>

#define NH    8
#define HD    64
#define NTOK  4096   // D*H*W = 16^3
#define CDIM  512
#define NSAMP 27

typedef __attribute__((ext_vector_type(8))) _Float16 half8;
typedef __attribute__((ext_vector_type(2))) _Float16 half2_t;
typedef __attribute__((ext_vector_type(4))) float floatx4;
typedef unsigned short ushort_t;

__device__ __forceinline__ ushort_t f16b(float f) {
  return __half_as_ushort(__float2half(f));
}
__device__ __forceinline__ __half2 u2h2(uint32_t u) { return __builtin_bit_cast(__half2, u); }
__device__ __forceinline__ uint32_t h22u(__half2 h) { return __builtin_bit_cast(uint32_t, h); }

// async global->LDS, 16B per lane (dest must be wave-uniform base + lane*16)
__device__ __forceinline__ void gl2lds16(const void* g, void* l) {
  __builtin_amdgcn_global_load_lds(
      (const __attribute__((address_space(1))) uint32_t*)g,
      (__attribute__((address_space(3))) uint32_t*)l, 16, 0, 0);
}

// ============ Kernel 0: fp32 -> f16 for x, w_qkv, w_proj, w_off, rel_* ============
__global__ __launch_bounds__(256) void k_cvt(const float* __restrict__ x,
                                             const float* __restrict__ wq,
                                             const float* __restrict__ wp,
                                             const float* __restrict__ w_off,
                                             const float* __restrict__ rel_d,
                                             const float* __restrict__ rel_h,
                                             const float* __restrict__ rel_w,
                                             ushort_t* __restrict__ xb,
                                             ushort_t* __restrict__ wqb,
                                             ushort_t* __restrict__ wpb,
                                             ushort_t* __restrict__ w_offh,
                                             ushort_t* __restrict__ relh) {
  int i = blockIdx.x * 256 + threadIdx.x;   // float4 index
  const float4* src = nullptr;
  ushort_t* dst;
  int off;
  float4 v = make_float4(0.f, 0.f, 0.f, 0.f);
  if (i < 524288)      { src = (const float4*)x;  dst = xb;  off = i; }
  else if (i < 720896) { src = (const float4*)wq; dst = wqb; off = i - 524288; }
  else if (i < 786432) { src = (const float4*)wp; dst = wpb; off = i - 720896; }
  else {
    int t = i - 786432;             // 0..4095
    if (t < 2048) {                 // w_offh [128][64], rows >= 81 zero
      off = t;
      int e = t * 4, row = e >> 6;
      if (row < 81) v = *(const float4*)&w_off[e];
      dst = w_offh;
    } else {                        // relh [128][64]: w | h | d | zero
      off = t - 2048;
      int e = off * 4, row = e >> 6, col = e & 63;
      if (row < 42)       v = *(const float4*)&rel_w[row * 64 + col];
      else if (row < 84)  v = *(const float4*)&rel_h[(row - 42) * 64 + col];
      else if (row < 126) v = *(const float4*)&rel_d[(row - 84) * 64 + col];
      dst = relh;
    }
  }
  if (src) v = src[off];
  ushort4 o = make_ushort4(f16b(v.x), f16b(v.y), f16b(v.z), f16b(v.w));
  *(ushort4*)&dst[(size_t)off * 4] = o;
}

// ============ Kernel 1: qkv GEMM, 64x128 tiles, BK=64, src-swizzled LDS (R8) ============
__global__ __launch_bounds__(256) void k_qkv(const ushort_t* __restrict__ Ah,
                                             const ushort_t* __restrict__ Bth,
                                             ushort_t* __restrict__ qh16,
                                             uint32_t* __restrict__ kvb) {
  __shared__ __align__(16) char smem[24576];
  ushort_t* As = (ushort_t*)smem;              // [64][64]
  ushort_t* Bs = (ushort_t*)(smem + 8192);     // [128][64]
  ushort_t* Cs = (ushort_t*)smem;              // [64][136] epilogue (aliases)
  const int tid = threadIdx.x;
  const int wave = tid >> 6, lane = tid & 63;
  const int wr = wave >> 1, wc = wave & 1;
  const int m15 = lane & 15, quad = lane >> 4;
  const int bm = blockIdx.x, bn = blockIdx.y;
  const bool is_q = (bn < 4);
  const int h = bn - 4;
  floatx4 acc[2][4];
#pragma unroll
  for (int i = 0; i < 2; i++)
#pragma unroll
    for (int j = 0; j < 4; j++) acc[i][j] = {0.f, 0.f, 0.f, 0.f};

  for (int k0 = 0; k0 < 512; k0 += 64) {
#pragma unroll
    for (int it = 0; it < 2; it++) {
      int id = it * 256 + tid, row = id >> 3, ch = id & 7;
      int sch = ch ^ (row & 7);
      gl2lds16(&Ah[(size_t)(bm * 64 + row) * 512 + k0 + sch * 8], &As[row * 64 + ch * 8]);
    }
#pragma unroll
    for (int it = 0; it < 4; it++) {
      int id = it * 256 + tid, row = id >> 3, ch = id & 7;
      int sch = ch ^ (row & 7);
      int srow = is_q ? (bn * 128 + row)
                      : (row < 64 ? 512 + h * 64 + row : 960 + h * 64 + row);
      gl2lds16(&Bth[(size_t)srow * 512 + k0 + sch * 8], &Bs[row * 64 + ch * 8]);
    }
    __syncthreads();
#pragma unroll
    for (int k4 = 0; k4 < 8; k4 += 4) {    // kk = k4*8 in {0,32}
      half8 af[2], bf[4];
#pragma unroll
      for (int i = 0; i < 2; i++) {
        int row = wr * 32 + i * 16 + m15;
        af[i] = *(const half8*)&As[row * 64 + ((quad + k4) ^ (row & 7)) * 8];
      }
#pragma unroll
      for (int j = 0; j < 4; j++) {
        int row = wc * 64 + j * 16 + m15;
        bf[j] = *(const half8*)&Bs[row * 64 + ((quad + k4) ^ (row & 7)) * 8];
      }
#pragma unroll
      for (int i = 0; i < 2; i++)
#pragma unroll
        for (int j = 0; j < 4; j++)
          acc[i][j] = __builtin_amdgcn_mfma_f32_16x16x32_f16(af[i], bf[j], acc[i][j], 0, 0, 0);
    }
    __syncthreads();
  }

  // stage C-tile (64 rows x 128 cols) to LDS as f16 (aliases As/Bs)
#pragma unroll
  for (int i = 0; i < 2; i++)
#pragma unroll
    for (int j = 0; j < 4; j++) {
      int col = wc * 64 + j * 16 + m15;
#pragma unroll
      for (int r = 0; r < 4; r++) {
        int row = wr * 32 + i * 16 + quad * 4 + r;
        Cs[row * 136 + col] = f16b(acc[i][j][r]);
      }
    }
  __syncthreads();

  if (is_q) {
#pragma unroll
    for (int it = 0; it < 4; it++) {
      int id = it * 256 + tid;
      int hh = id >> 9, row = (id >> 3) & 63, chunk = id & 7;
      uint4 d = *(const uint4*)&Cs[row * 136 + hh * 64 + chunk * 8];
      int hq = bn * 2 + hh;
      *(uint4*)&qh16[((size_t)hq * NTOK + bm * 64 + row) * 64 + chunk * 8] = d;
    }
  } else {
#pragma unroll
    for (int it = 0; it < 4; it++) {
      int id = it * 256 + tid;
      int row = id >> 4, chunk = id & 15;
      uint2 kk = *(const uint2*)&Cs[row * 136 + chunk * 4];
      uint2 vv = *(const uint2*)&Cs[row * 136 + 64 + chunk * 4];
      uint4 o;
      o.x = (kk.x & 0xffffu) | (vv.x << 16);
      o.y = (kk.x >> 16) | (vv.x & 0xffff0000u);
      o.z = (kk.y & 0xffffu) | (vv.y << 16);
      o.w = (kk.y >> 16) | (vv.y & 0xffff0000u);
      *(uint4*)&kvb[((size_t)h * NTOK + bm * 64 + row) * 64 + chunk * 4] = o;
    }
  }
}

// ============ Kernel 2: merged off/pos GEMMs, K=64 in ONE stage (R8) ============
__global__ __launch_bounds__(256) void k_aux(const ushort_t* __restrict__ xh,
                                             const ushort_t* __restrict__ qh16,
                                             const ushort_t* __restrict__ w_offh,
                                             const ushort_t* __restrict__ relh,
                                             float* __restrict__ ob,
                                             float* __restrict__ Pb) {
  __shared__ __align__(16) ushort_t As[128 * 64];
  __shared__ __align__(16) ushort_t Bs[128 * 64];
  const int tid = threadIdx.x;
  const int wave = tid >> 6, lane = tid & 63;
  const int wr = wave >> 1, wc = wave & 1;
  const int m15 = lane & 15, quad = lane >> 4;
  const int bm = blockIdx.x;
  const int mode = blockIdx.y >> 3, h = blockIdx.y & 7;

  const ushort_t* A;  int lda;
  const ushort_t* B;
  float* C;  int NC;
  if (mode == 0) { A = xh + h * 64;                  lda = 512; B = w_offh; C = ob + (size_t)h * NTOK * 81;  NC = 81; }
  else           { A = qh16 + (size_t)h * NTOK * 64; lda = 64;  B = relh;   C = Pb + (size_t)h * NTOK * 126; NC = 126; }

#pragma unroll
  for (int it = 0; it < 4; it++) {
    int id = it * 256 + tid, row = id >> 3, ch = id & 7;
    int sch = ch ^ (row & 7);
    gl2lds16(&A[(size_t)(bm * 128 + row) * lda + sch * 8], &As[row * 64 + ch * 8]);
    gl2lds16(&B[(size_t)row * 64 + sch * 8], &Bs[row * 64 + ch * 8]);
  }
  __syncthreads();

  floatx4 acc[4][4];
#pragma unroll
  for (int i = 0; i < 4; i++)
#pragma unroll
    for (int j = 0; j < 4; j++) acc[i][j] = {0.f, 0.f, 0.f, 0.f};

#pragma unroll
  for (int k4 = 0; k4 < 8; k4 += 4) {      // kk in {0,32}
    half8 af[4], bf[4];
#pragma unroll
    for (int i = 0; i < 4; i++) {
      int row = wr * 64 + i * 16 + m15;
      af[i] = *(const half8*)&As[row * 64 + ((quad + k4) ^ (row & 7)) * 8];
    }
#pragma unroll
    for (int j = 0; j < 4; j++) {
      int row = wc * 64 + j * 16 + m15;
      bf[j] = *(const half8*)&Bs[row * 64 + ((quad + k4) ^ (row & 7)) * 8];
    }
#pragma unroll
    for (int i = 0; i < 4; i++)
#pragma unroll
      for (int j = 0; j < 4; j++)
        acc[i][j] = __builtin_amdgcn_mfma_f32_16x16x32_f16(af[i], bf[j], acc[i][j], 0, 0, 0);
  }

#pragma unroll
  for (int i = 0; i < 4; i++)
#pragma unroll
    for (int j = 0; j < 4; j++) {
      int col = wc * 64 + j * 16 + m15;
      if (col < NC) {
#pragma unroll
        for (int r = 0; r < 4; r++) {
          int row = bm * 128 + wr * 64 + i * 16 + quad * 4 + r;
          C[(size_t)row * NC + col] = acc[i][j][r];
        }
      }
    }
}

// ============ Kernel 3: fused deformable attention — shared LDS kv-window ============
// Block = 4 consecutive-x queries of one head. All 216 corner reads per query land
// in a 5x5x8-voxel window (|offset| < 1 for this input); stage it ONCE per block
// (50 KB via gl2lds16, per-lane global src + linear LDS dst), then corner reads are
// ds_read_b128 with a linear-equivalent bank pattern. Compute pipeline = R8.
__global__ __launch_bounds__(256) void k_attn(const ushort_t* __restrict__ qh16,
                                              const uint32_t* __restrict__ kvb,
                                              const float* __restrict__ obuf,
                                              const float* __restrict__ Pbuf,
                                              ushort_t* __restrict__ attb16) {
  __shared__ __align__(16) char     win[25 * 8 * 256];  // 51200 B kv window
  __shared__ __align__(16) int      s_off[4][28][8];    // LDS byte offsets into win
  __shared__ __align__(16) uint32_t s_cwh[4][28][8];    // half2(w,w) splats
  __shared__ __align__(16) uint32_t vs_lds[4][28][32];  // gathered v per sample
  __shared__ float s_dot[4][28];                        // q . ks[s]
  __shared__ uint32_t s_wp[4][14];                      // half2(w[2p], w[2p+1])
  const int bid = blockIdx.x;
  const int h = bid & 7;
  const int tid = threadIdx.x;
  const int wave = tid >> 6;
  const int lane = tid & 63;
  const int n = (bid >> 3) * 4 + wave;
  const int z = n >> 8, y = (n >> 4) & 15, xq = n & 15;
  const int jb = (bid >> 3) & 3;                        // x-block: xq = 4*jb + wave
  const int xlo = (jb == 0) ? 0 : ((jb == 3) ? 8 : 4 * jb - 2);
  const int m = lane & 15;
  const char* kvc = (const char*)(kvb + (size_t)h * NTOK * 64);
  const uint32_t laneb = (uint32_t)m * 16u;             // within-row byte offset

  // ---- stage the 25 x (8 voxels = 2KB) window segments (async) ----
#pragma unroll
  for (int p = 0; p < 13; ++p) {
    int id = p * 256 + tid;                             // 16B chunk index, < 3200
    if (id < 3200) {
      int seg = id >> 7, within = id & 127;
      int zc = min(max(z - 2 + seg / 5, 0), 15);
      int yc = min(max(y - 2 + seg % 5, 0), 15);
      gl2lds16(kvc + (size_t)(((zc * 16 + yc) * 16 + xlo) * 256 + within * 16),
               win + id * 16);
    }
  }

  // q channels 4m..4m+3 (two packed half2)
  const uint2 qp = *(const uint2*)&qh16[((size_t)h * NTOK + n) * 64 + m * 4];
  const half2_t q01 = __builtin_bit_cast(half2_t, qp.x);
  const half2_t q23 = __builtin_bit_cast(half2_t, qp.y);

  if (lane < 28) {
    const int s = lane;
    int      oarr[8];
    uint32_t warr[8];
    if (s < NSAMP) {
      const float* op = &obuf[((size_t)h * NTOK + n) * 81 + s * 3];
      float oz = op[0], oy = op[1], ox = op[2];
      float pz = (float)(z + (s / 9) - 1) + oz;
      float py = (float)(y + ((s / 3) % 3) - 1) + oy;
      float px = (float)(xq + (s % 3) - 1) + ox;
      float fz = floorf(pz), fy = floorf(py), fx = floorf(px);
      float wz = pz - fz, wy = py - fy, wx = px - fx;
      int z0 = (int)fz, y0 = (int)fy, x0 = (int)fx;
#pragma unroll
      for (int c = 0; c < 8; c++) {
        int dz = (c >> 2) & 1, dy = (c >> 1) & 1, dx = c & 1;
        int zi = z0 + dz, yi = y0 + dy, xi = x0 + dx;
        bool valid = (zi >= 0) && (zi < 16) && (yi >= 0) && (yi < 16) && (xi >= 0) && (xi < 16);
        float w = (dz ? wz : 1.f - wz) * (dy ? wy : 1.f - wy) * (dx ? wx : 1.f - wx);
        int iz = min(max(zi - z + 2, 0), 4);            // window coords
        int iy = min(max(yi - y + 2, 0), 4);
        int ix = min(max(min(max(xi, 0), 15) - xlo, 0), 7);
        oarr[c] = ((iz * 5 + iy) * 8 + ix) * 256;       // LDS byte offset of voxel row
        uint32_t hw = (uint32_t)f16b(valid ? w : 0.f);
        warr[c] = hw | (hw << 16);                      // half2(w, w)
      }
    } else {
#pragma unroll
      for (int c = 0; c < 8; c++) { oarr[c] = 0; warr[c] = 0u; }
    }
    *(int4*)&s_off[wave][s][0]  = make_int4(oarr[0], oarr[1], oarr[2], oarr[3]);
    *(int4*)&s_off[wave][s][4]  = make_int4(oarr[4], oarr[5], oarr[6], oarr[7]);
    *(uint4*)&s_cwh[wave][s][0] = make_uint4(warr[0], warr[1], warr[2], warr[3]);
    *(uint4*)&s_cwh[wave][s][4] = make_uint4(warr[4], warr[5], warr[6], warr[7]);
  }

  // hoist the scattered pos-embedding loads above the gather loop (latency hiding)
  float pos = 0.f;
  if (lane < NSAMP) {
    int j = 15 + lane - xq;
    int n2 = (z * 16 + xq) * 16 + y;
    int n3 = (xq * 16 + z) * 16 + y;
    pos = Pbuf[((size_t)h * NTOK + n) * 126 + j]
        + Pbuf[((size_t)h * NTOK + n2) * 126 + 42 + j]
        + Pbuf[((size_t)h * NTOK + n3) * 126 + 84 + j];
  }

  __syncthreads();   // window staged (drains gl2lds16), s_off visible per-wave

  const int g = lane >> 4;
#define LDW(OV) (*(const uint4*)(win + (uint32_t)(OV) + laneb))
#pragma unroll 2
  for (int t = 0; t < 7; ++t) {
    const int s = t * 4 + g;
    int4  o0 = *(const int4*)&s_off[wave][s][0];
    int4  o1 = *(const int4*)&s_off[wave][s][4];
    uint4 c0 = *(const uint4*)&s_cwh[wave][s][0];
    uint4 c1 = *(const uint4*)&s_cwh[wave][s][4];
    __half2 a0 = u2h2(0u), a1 = u2h2(0u), a2 = u2h2(0u), a3 = u2h2(0u);
#define CORNER(OV, WV)                                                        \
    { uint4 p = LDW(OV);                                                      \
      __half2 w2 = u2h2(WV);                                                  \
      a0 = __hfma2(w2, u2h2(p.x), a0); a1 = __hfma2(w2, u2h2(p.y), a1);       \
      a2 = __hfma2(w2, u2h2(p.z), a2); a3 = __hfma2(w2, u2h2(p.w), a3); }
    CORNER(o0.x, c0.x) CORNER(o0.y, c0.y) CORNER(o0.z, c0.z) CORNER(o0.w, c0.w)
    CORNER(o1.x, c1.x) CORNER(o1.y, c1.y) CORNER(o1.z, c1.z) CORNER(o1.w, c1.w)
#undef CORNER
    // k sits in LOW halves, v in HIGH halves of a0..a3
    uint32_t u0 = h22u(a0), u1 = h22u(a1), u2 = h22u(a2), u3 = h22u(a3);
    uint32_t kk01 = (u0 & 0xffffu) | (u1 << 16);
    uint32_t kk23 = (u2 & 0xffffu) | (u3 << 16);
    uint32_t vv01 = (u0 >> 16) | (u1 & 0xffff0000u);
    uint32_t vv23 = (u2 >> 16) | (u3 & 0xffff0000u);
    *(uint2*)&vs_lds[wave][s][m * 2] = make_uint2(vv01, vv23);
    float x = __builtin_amdgcn_fdot2(__builtin_bit_cast(half2_t, kk01), q01,
              __builtin_amdgcn_fdot2(__builtin_bit_cast(half2_t, kk23), q23, 0.f, false), false);
    // 16-lane prefix sum via DPP row_shr; lane15 of each row = group total
#define DPP_ADD(ctrl)                                                            \
    { int t_ = __builtin_amdgcn_update_dpp(0, __float_as_int(x), ctrl, 0xf, 0xf, \
                                           true);                                \
      x += __int_as_float(t_); }
    DPP_ADD(0x111) DPP_ADD(0x112) DPP_ADD(0x114) DPP_ADD(0x118)
#undef DPP_ADD
    if ((lane & 15) == 15) s_dot[wave][s] = x;
  }
#undef LDW

  float logit = (lane < NSAMP) ? s_dot[wave][lane] * 0.125f + pos : -INFINITY;

  // softmax over lanes 0..26
  float mx = logit;
#pragma unroll
  for (int off = 16; off >= 1; off >>= 1) mx = fmaxf(mx, __shfl_xor(mx, off, 64));
  float e = __expf(logit - mx);            // lanes >= 27: exp(-inf) = 0
  float sum = e;
#pragma unroll
  for (int off = 16; off >= 1; off >>= 1) sum += __shfl_xor(sum, off, 64);
  const float wgt = e / sum;

  // pack weight pairs for the PV stage
  uint32_t hw = (uint32_t)f16b(wgt);                       // lanes>=27 -> 0
  uint32_t nw = (uint32_t)__shfl_down((int)hw, 1, 64);     // next lane's weight
  if ((lane & 1) == 0 && lane < 28)
    s_wp[wave][lane >> 1] = hw | (nw << 16);

  // PV: lane = output channel; pair samples (2p, 2p+1) via v_perm + packed fma
  const uint32_t selu = (lane & 1) ? 0x03020706u : 0x01000504u;
  const uint32_t* vbase = &vs_lds[wave][0][lane >> 1];
  __half2 out2 = u2h2(0u);
#pragma unroll
  for (int p = 0; p < 14; ++p) {
    uint32_t d0 = vbase[(2 * p) * 32];
    uint32_t d1 = vbase[(2 * p + 1) * 32];
    uint32_t pk;
    asm("v_perm_b32 %0, %1, %2, %3" : "=v"(pk) : "v"(d0), "v"(d1), "v"(selu));
    out2 = __hfma2(u2h2(s_wp[wave][p]), u2h2(pk), out2);
  }
  float out = __half2float(out2.x) + __half2float(out2.y);
  attb16[(size_t)n * 512 + h * 64 + lane] = f16b(out);
}

// ============ Kernel 4: proj GEMM, 64x64 tiles, BK=64, src-swizzled LDS (R8) ============
__global__ __launch_bounds__(256) void k_proj(const ushort_t* __restrict__ Ah,
                                              const ushort_t* __restrict__ Bth,
                                              const float* __restrict__ bias,
                                              float* __restrict__ out) {
  __shared__ __align__(16) ushort_t As[64 * 64];
  __shared__ __align__(16) ushort_t Bs[64 * 64];
  const int tid = threadIdx.x;
  const int wave = tid >> 6, lane = tid & 63;
  const int wr = wave >> 1, wc = wave & 1;
  const int m15 = lane & 15, quad = lane >> 4;
  const int bm = blockIdx.x, bn = blockIdx.y;
  floatx4 acc[2][2];
#pragma unroll
  for (int i = 0; i < 2; i++)
#pragma unroll
    for (int j = 0; j < 2; j++) acc[i][j] = {0.f, 0.f, 0.f, 0.f};

  for (int k0 = 0; k0 < 512; k0 += 64) {
#pragma unroll
    for (int it = 0; it < 2; it++) {
      int id = it * 256 + tid, row = id >> 3, ch = id & 7;
      int sch = ch ^ (row & 7);
      gl2lds16(&Ah[(size_t)(bm * 64 + row) * 512 + k0 + sch * 8],  &As[row * 64 + ch * 8]);
      gl2lds16(&Bth[(size_t)(bn * 64 + row) * 512 + k0 + sch * 8], &Bs[row * 64 + ch * 8]);
    }
    __syncthreads();
#pragma unroll
    for (int k4 = 0; k4 < 8; k4 += 4) {    // kk in {0,32}
      half8 af[2], bf[2];
#pragma unroll
      for (int i = 0; i < 2; i++) {
        int row = wr * 32 + i * 16 + m15;
        af[i] = *(const half8*)&As[row * 64 + ((quad + k4) ^ (row & 7)) * 8];
      }
#pragma unroll
      for (int j = 0; j < 2; j++) {
        int row = wc * 32 + j * 16 + m15;
        bf[j] = *(const half8*)&Bs[row * 64 + ((quad + k4) ^ (row & 7)) * 8];
      }
#pragma unroll
      for (int i = 0; i < 2; i++)
#pragma unroll
        for (int j = 0; j < 2; j++)
          acc[i][j] = __builtin_amdgcn_mfma_f32_16x16x32_f16(af[i], bf[j], acc[i][j], 0, 0, 0);
    }
    __syncthreads();
  }

#pragma unroll
  for (int i = 0; i < 2; i++)
#pragma unroll
    for (int j = 0; j < 2; j++) {
      int col = bn * 64 + wc * 32 + j * 16 + m15;
      float b = bias[col];
#pragma unroll
      for (int r = 0; r < 4; r++) {
        int row = bm * 64 + wr * 32 + i * 16 + quad * 4 + r;
        out[(size_t)row * 512 + col] = acc[i][j][r] + b;
      }
    }
}

extern "C" void kernel_launch(void* const* d_in, const int* in_sizes, int n_in,
                              void* d_out, int out_size, void* d_ws, size_t ws_size,
                              hipStream_t stream) {
  const float* x      = (const float*)d_in[0];
  const float* w_qkv  = (const float*)d_in[1];
  const float* w_proj = (const float*)d_in[2];
  const float* b_proj = (const float*)d_in[3];
  const float* w_off  = (const float*)d_in[4];
  const float* rel_d  = (const float*)d_in[5];
  const float* rel_h  = (const float*)d_in[6];
  const float* rel_w  = (const float*)d_in[7];

  char* ws = (char*)d_ws;
  uint32_t* kvb    = (uint32_t*)ws; ws += (size_t)NH * NTOK * 64 * 4;
  float*    ob     = (float*)ws;    ws += (size_t)NH * NTOK * 81 * 4;
  float*    Pb     = (float*)ws;    ws += (size_t)NH * NTOK * 126 * 4;
  ushort_t* attb16 = (ushort_t*)ws; ws += (size_t)NTOK * CDIM * 2;
  ushort_t* xh     = (ushort_t*)ws; ws += (size_t)NTOK * CDIM * 2;
  ushort_t* wqh    = (ushort_t*)ws; ws += (size_t)3 * CDIM * CDIM * 2;
  ushort_t* wph    = (ushort_t*)ws; ws += (size_t)CDIM * CDIM * 2;
  ushort_t* qh16   = (ushort_t*)ws; ws += (size_t)NH * NTOK * 64 * 2;
  ushort_t* w_offh = (ushort_t*)ws; ws += (size_t)128 * 64 * 2;
  ushort_t* relh   = (ushort_t*)ws; ws += (size_t)128 * 64 * 2;
  float*    out    = (float*)d_out;

  k_cvt <<<dim3(3088), dim3(256), 0, stream>>>(x, w_qkv, w_proj, w_off, rel_d, rel_h,
                                               rel_w, xh, wqh, wph, w_offh, relh);
  k_qkv <<<dim3(64, 12), dim3(256), 0, stream>>>(xh, wqh, qh16, kvb);
  k_aux <<<dim3(32, 16), dim3(256), 0, stream>>>(xh, qh16, w_offh, relh, ob, Pb);
  k_attn<<<dim3(8192),   dim3(256), 0, stream>>>(qh16, kvb, ob, Pb, attb16);
  k_proj<<<dim3(64, 8),  dim3(256), 0, stream>>>(attb16, wph, b_proj, out);
}

// Round 12
// 164.360 us; speedup vs baseline: 1.1584x; 1.1584x over previous
//
#include <hip/hip_runtime.h>
#include <hip/hip_fp16.h>
#include <math.h>
#include <stdint.h>

#define NH    8
#define HD    64
#define NTOK  4096   // D*H*W = 16^3
#define CDIM  512
#define NSAMP 27

typedef __attribute__((ext_vector_type(8))) _Float16 half8;
typedef __attribute__((ext_vector_type(2))) _Float16 half2_t;
typedef __attribute__((ext_vector_type(4))) float floatx4;
typedef unsigned short ushort_t;

__device__ __forceinline__ ushort_t f16b(float f) {
  return __half_as_ushort(__float2half(f));
}
__device__ __forceinline__ __half2 u2h2(uint32_t u) { return __builtin_bit_cast(__half2, u); }
__device__ __forceinline__ uint32_t h22u(__half2 h) { return __builtin_bit_cast(uint32_t, h); }

// async global->LDS, 16B per lane (dest must be wave-uniform base + lane*16)
__device__ __forceinline__ void gl2lds16(const void* g, void* l) {
  __builtin_amdgcn_global_load_lds(
      (const __attribute__((address_space(1))) uint32_t*)g,
      (__attribute__((address_space(3))) uint32_t*)l, 16, 0, 0);
}

// ============ Kernel 0: fp32 -> f16 for x, w_qkv, w_proj, w_off, rel_* ============
__global__ __launch_bounds__(256) void k_cvt(const float* __restrict__ x,
                                             const float* __restrict__ wq,
                                             const float* __restrict__ wp,
                                             const float* __restrict__ w_off,
                                             const float* __restrict__ rel_d,
                                             const float* __restrict__ rel_h,
                                             const float* __restrict__ rel_w,
                                             ushort_t* __restrict__ xb,
                                             ushort_t* __restrict__ wqb,
                                             ushort_t* __restrict__ wpb,
                                             ushort_t* __restrict__ w_offh,
                                             ushort_t* __restrict__ relh) {
  int i = blockIdx.x * 256 + threadIdx.x;   // float4 index
  const float4* src = nullptr;
  ushort_t* dst;
  int off;
  float4 v = make_float4(0.f, 0.f, 0.f, 0.f);
  if (i < 524288)      { src = (const float4*)x;  dst = xb;  off = i; }
  else if (i < 720896) { src = (const float4*)wq; dst = wqb; off = i - 524288; }
  else if (i < 786432) { src = (const float4*)wp; dst = wpb; off = i - 720896; }
  else {
    int t = i - 786432;             // 0..4095
    if (t < 2048) {                 // w_offh [128][64], rows >= 81 zero
      off = t;
      int e = t * 4, row = e >> 6;
      if (row < 81) v = *(const float4*)&w_off[e];
      dst = w_offh;
    } else {                        // relh [128][64]: w | h | d | zero
      off = t - 2048;
      int e = off * 4, row = e >> 6, col = e & 63;
      if (row < 42)       v = *(const float4*)&rel_w[row * 64 + col];
      else if (row < 84)  v = *(const float4*)&rel_h[(row - 42) * 64 + col];
      else if (row < 126) v = *(const float4*)&rel_d[(row - 84) * 64 + col];
      dst = relh;
    }
  }
  if (src) v = src[off];
  ushort4 o = make_ushort4(f16b(v.x), f16b(v.y), f16b(v.z), f16b(v.w));
  *(ushort4*)&dst[(size_t)off * 4] = o;
}

// ============ Kernel 1: qkv GEMM, 64x128 tiles, BK=64, src-swizzled LDS ============
// bn 0..3: q col-tiles. bn 4..11: head h=bn-4 kv tile -> packed kv dwords.
// LDS rows are 64 f16 (128 B): source chunk XOR-swizzled by (row&7), read with
// matching XOR -> 2-way bank conflicts (free). 8 K-steps (16 barriers vs 32).
__global__ __launch_bounds__(256) void k_qkv(const ushort_t* __restrict__ Ah,
                                             const ushort_t* __restrict__ Bth,
                                             ushort_t* __restrict__ qh16,
                                             uint32_t* __restrict__ kvb) {
  __shared__ __align__(16) char smem[24576];
  ushort_t* As = (ushort_t*)smem;              // [64][64]
  ushort_t* Bs = (ushort_t*)(smem + 8192);     // [128][64]
  ushort_t* Cs = (ushort_t*)smem;              // [64][136] epilogue (aliases)
  const int tid = threadIdx.x;
  const int wave = tid >> 6, lane = tid & 63;
  const int wr = wave >> 1, wc = wave & 1;
  const int m15 = lane & 15, quad = lane >> 4;
  const int bm = blockIdx.x, bn = blockIdx.y;
  const bool is_q = (bn < 4);
  const int h = bn - 4;
  floatx4 acc[2][4];
#pragma unroll
  for (int i = 0; i < 2; i++)
#pragma unroll
    for (int j = 0; j < 4; j++) acc[i][j] = {0.f, 0.f, 0.f, 0.f};

  for (int k0 = 0; k0 < 512; k0 += 64) {
    // A: 512 chunks (64 rows x 8 chunks)
#pragma unroll
    for (int it = 0; it < 2; it++) {
      int id = it * 256 + tid, row = id >> 3, ch = id & 7;
      int sch = ch ^ (row & 7);
      gl2lds16(&Ah[(size_t)(bm * 64 + row) * 512 + k0 + sch * 8], &As[row * 64 + ch * 8]);
    }
    // B: 1024 chunks (128 rows x 8 chunks)
#pragma unroll
    for (int it = 0; it < 4; it++) {
      int id = it * 256 + tid, row = id >> 3, ch = id & 7;
      int sch = ch ^ (row & 7);
      int srow = is_q ? (bn * 128 + row)
                      : (row < 64 ? 512 + h * 64 + row : 960 + h * 64 + row);
      gl2lds16(&Bth[(size_t)srow * 512 + k0 + sch * 8], &Bs[row * 64 + ch * 8]);
    }
    __syncthreads();
#pragma unroll
    for (int k4 = 0; k4 < 8; k4 += 4) {    // kk = k4*8 in {0,32}
      half8 af[2], bf[4];
#pragma unroll
      for (int i = 0; i < 2; i++) {
        int row = wr * 32 + i * 16 + m15;
        af[i] = *(const half8*)&As[row * 64 + ((quad + k4) ^ (row & 7)) * 8];
      }
#pragma unroll
      for (int j = 0; j < 4; j++) {
        int row = wc * 64 + j * 16 + m15;
        bf[j] = *(const half8*)&Bs[row * 64 + ((quad + k4) ^ (row & 7)) * 8];
      }
#pragma unroll
      for (int i = 0; i < 2; i++)
#pragma unroll
        for (int j = 0; j < 4; j++)
          acc[i][j] = __builtin_amdgcn_mfma_f32_16x16x32_f16(af[i], bf[j], acc[i][j], 0, 0, 0);
    }
    __syncthreads();
  }

  // stage C-tile (64 rows x 128 cols) to LDS as f16 (aliases As/Bs)
#pragma unroll
  for (int i = 0; i < 2; i++)
#pragma unroll
    for (int j = 0; j < 4; j++) {
      int col = wc * 64 + j * 16 + m15;
#pragma unroll
      for (int r = 0; r < 4; r++) {
        int row = wr * 32 + i * 16 + quad * 4 + r;
        Cs[row * 136 + col] = f16b(acc[i][j][r]);
      }
    }
  __syncthreads();

  if (is_q) {
#pragma unroll
    for (int it = 0; it < 4; it++) {
      int id = it * 256 + tid;
      int hh = id >> 9, row = (id >> 3) & 63, chunk = id & 7;
      uint4 d = *(const uint4*)&Cs[row * 136 + hh * 64 + chunk * 8];
      int hq = bn * 2 + hh;
      *(uint4*)&qh16[((size_t)hq * NTOK + bm * 64 + row) * 64 + chunk * 8] = d;
    }
  } else {
#pragma unroll
    for (int it = 0; it < 4; it++) {
      int id = it * 256 + tid;
      int row = id >> 4, chunk = id & 15;
      uint2 kk = *(const uint2*)&Cs[row * 136 + chunk * 4];
      uint2 vv = *(const uint2*)&Cs[row * 136 + 64 + chunk * 4];
      uint4 o;
      o.x = (kk.x & 0xffffu) | (vv.x << 16);
      o.y = (kk.x >> 16) | (vv.x & 0xffff0000u);
      o.z = (kk.y & 0xffffu) | (vv.y << 16);
      o.w = (kk.y >> 16) | (vv.y & 0xffff0000u);
      *(uint4*)&kvb[((size_t)h * NTOK + bm * 64 + row) * 64 + chunk * 4] = o;
    }
  }
}

// ============ Kernel 2: merged off/pos GEMMs, K=64 in ONE stage (1 barrier) ============
__global__ __launch_bounds__(256) void k_aux(const ushort_t* __restrict__ xh,
                                             const ushort_t* __restrict__ qh16,
                                             const ushort_t* __restrict__ w_offh,
                                             const ushort_t* __restrict__ relh,
                                             float* __restrict__ ob,
                                             float* __restrict__ Pb) {
  __shared__ __align__(16) ushort_t As[128 * 64];
  __shared__ __align__(16) ushort_t Bs[128 * 64];
  const int tid = threadIdx.x;
  const int wave = tid >> 6, lane = tid & 63;
  const int wr = wave >> 1, wc = wave & 1;
  const int m15 = lane & 15, quad = lane >> 4;
  const int bm = blockIdx.x;
  const int mode = blockIdx.y >> 3, h = blockIdx.y & 7;

  const ushort_t* A;  int lda;
  const ushort_t* B;
  float* C;  int NC;
  if (mode == 0) { A = xh + h * 64;                  lda = 512; B = w_offh; C = ob + (size_t)h * NTOK * 81;  NC = 81; }
  else           { A = qh16 + (size_t)h * NTOK * 64; lda = 64;  B = relh;   C = Pb + (size_t)h * NTOK * 126; NC = 126; }

  // stage entire 128x64 A and B tiles (src-swizzled), single barrier
#pragma unroll
  for (int it = 0; it < 4; it++) {
    int id = it * 256 + tid, row = id >> 3, ch = id & 7;
    int sch = ch ^ (row & 7);
    gl2lds16(&A[(size_t)(bm * 128 + row) * lda + sch * 8], &As[row * 64 + ch * 8]);
    gl2lds16(&B[(size_t)row * 64 + sch * 8], &Bs[row * 64 + ch * 8]);
  }
  __syncthreads();

  floatx4 acc[4][4];
#pragma unroll
  for (int i = 0; i < 4; i++)
#pragma unroll
    for (int j = 0; j < 4; j++) acc[i][j] = {0.f, 0.f, 0.f, 0.f};

#pragma unroll
  for (int k4 = 0; k4 < 8; k4 += 4) {      // kk in {0,32}
    half8 af[4], bf[4];
#pragma unroll
    for (int i = 0; i < 4; i++) {
      int row = wr * 64 + i * 16 + m15;
      af[i] = *(const half8*)&As[row * 64 + ((quad + k4) ^ (row & 7)) * 8];
    }
#pragma unroll
    for (int j = 0; j < 4; j++) {
      int row = wc * 64 + j * 16 + m15;
      bf[j] = *(const half8*)&Bs[row * 64 + ((quad + k4) ^ (row & 7)) * 8];
    }
#pragma unroll
    for (int i = 0; i < 4; i++)
#pragma unroll
      for (int j = 0; j < 4; j++)
        acc[i][j] = __builtin_amdgcn_mfma_f32_16x16x32_f16(af[i], bf[j], acc[i][j], 0, 0, 0);
  }

#pragma unroll
  for (int i = 0; i < 4; i++)
#pragma unroll
    for (int j = 0; j < 4; j++) {
      int col = wc * 64 + j * 16 + m15;
      if (col < NC) {
#pragma unroll
        for (int r = 0; r < 4; r++) {
          int row = bm * 128 + wr * 64 + i * 16 + quad * 4 + r;
          C[(size_t)row * NC + col] = acc[i][j][r];
        }
      }
    }
}

// ============ Kernel 3: fused deformable attention (R5/R8 1-deep, proven) ============
__global__ __launch_bounds__(256) void k_attn(const ushort_t* __restrict__ qh16,
                                              const uint32_t* __restrict__ kvb,
                                              const float* __restrict__ obuf,
                                              const float* __restrict__ Pbuf,
                                              ushort_t* __restrict__ attb16) {
  __shared__ __align__(16) int      s_off[4][32][8];   // BYTE offsets (voxel*256)
  __shared__ __align__(16) uint32_t s_cwh[4][32][8];   // half2(w,w) splats
  __shared__ __align__(16) uint32_t vs_lds[4][28][32]; // per sample: 64 ch of v as ch-pair dwords
  __shared__ float s_dot[4][28];                       // q . ks[s]
  __shared__ uint32_t s_wp[4][14];                     // half2(w[2p], w[2p+1])
  const int bid = blockIdx.x;
  const int h = bid & 7;
  const int wave = threadIdx.x >> 6;
  const int lane = threadIdx.x & 63;
  const int n = (bid >> 3) * 4 + wave;
  const int z = n >> 8, y = (n >> 4) & 15, xq = n & 15;
  const int m = lane & 15;          // dword-quad index: channels 4m..4m+3
  const char* kvc = (const char*)(kvb + (size_t)h * NTOK * 64);
  const uint32_t laneb = (uint32_t)m * 16u;   // byte offset within 256B voxel row

  // q channels 4m..4m+3 (two packed half2)
  const uint2 qp = *(const uint2*)&qh16[((size_t)h * NTOK + n) * 64 + m * 4];
  const half2_t q01 = __builtin_bit_cast(half2_t, qp.x);
  const half2_t q23 = __builtin_bit_cast(half2_t, qp.y);

  if (lane < 32) {
    const int s = lane;
    int      oarr[8];
    uint32_t warr[8];
    if (s < NSAMP) {
      const float* op = &obuf[((size_t)h * NTOK + n) * 81 + s * 3];
      float oz = op[0], oy = op[1], ox = op[2];
      float pz = (float)(z + (s / 9) - 1) + oz;
      float py = (float)(y + ((s / 3) % 3) - 1) + oy;
      float px = (float)(xq + (s % 3) - 1) + ox;
      float fz = floorf(pz), fy = floorf(py), fx = floorf(px);
      float wz = pz - fz, wy = py - fy, wx = px - fx;
      int z0 = (int)fz, y0 = (int)fy, x0 = (int)fx;
#pragma unroll
      for (int c = 0; c < 8; c++) {
        int dz = (c >> 2) & 1, dy = (c >> 1) & 1, dx = c & 1;
        int zi = z0 + dz, yi = y0 + dy, xi = x0 + dx;
        bool valid = (zi >= 0) && (zi < 16) && (yi >= 0) && (yi < 16) && (xi >= 0) && (xi < 16);
        float w = (dz ? wz : 1.f - wz) * (dy ? wy : 1.f - wy) * (dx ? wx : 1.f - wx);
        int zc = min(max(zi, 0), 15), yc = min(max(yi, 0), 15), xc = min(max(xi, 0), 15);
        oarr[c] = ((zc * 16 + yc) * 16 + xc) * 256;       // byte offset of voxel row
        uint32_t hw = (uint32_t)f16b(valid ? w : 0.f);
        warr[c] = hw | (hw << 16);                        // half2(w, w)
      }
    } else {
#pragma unroll
      for (int c = 0; c < 8; c++) { oarr[c] = 0; warr[c] = 0u; }
    }
    *(int4*)&s_off[wave][s][0]  = make_int4(oarr[0], oarr[1], oarr[2], oarr[3]);
    *(int4*)&s_off[wave][s][4]  = make_int4(oarr[4], oarr[5], oarr[6], oarr[7]);
    *(uint4*)&s_cwh[wave][s][0] = make_uint4(warr[0], warr[1], warr[2], warr[3]);
    *(uint4*)&s_cwh[wave][s][4] = make_uint4(warr[4], warr[5], warr[6], warr[7]);
  }
  // no __syncthreads: producers/consumers are the same wave (in-order ds)

  // hoist the scattered pos-embedding loads above the gather loop (latency hiding)
  float pos = 0.f;
  if (lane < NSAMP) {
    int j = 15 + lane - xq;
    int n2 = (z * 16 + xq) * 16 + y;
    int n3 = (xq * 16 + z) * 16 + y;
    pos = Pbuf[((size_t)h * NTOK + n) * 126 + j]
        + Pbuf[((size_t)h * NTOK + n2) * 126 + 42 + j]
        + Pbuf[((size_t)h * NTOK + n3) * 126 + 84 + j];
  }

  const int g = lane >> 4;
#define LDKV(OV) (*(const uint4*)(kvc + (uint32_t)((uint32_t)(OV) + laneb)))
  int4  o0 = *(const int4*)&s_off[wave][g][0];
  int4  o1 = *(const int4*)&s_off[wave][g][4];
  uint4 c0 = *(const uint4*)&s_cwh[wave][g][0];
  uint4 c1 = *(const uint4*)&s_cwh[wave][g][4];
  uint4 P0 = LDKV(o0.x), P1 = LDKV(o0.y), P2 = LDKV(o0.z), P3 = LDKV(o0.w);
  uint4 P4 = LDKV(o1.x), P5 = LDKV(o1.y), P6 = LDKV(o1.z), P7 = LDKV(o1.w);

#pragma unroll 2
  for (int t = 0; t < 7; ++t) {
    const int s = t * 4 + g;
    // prefetch next sample's metadata + issue its 8 loads (rows 28..31 are zeroed dummies)
    int4  no0 = *(const int4*)&s_off[wave][s + 4][0];
    int4  no1 = *(const int4*)&s_off[wave][s + 4][4];
    uint4 nc0 = *(const uint4*)&s_cwh[wave][s + 4][0];
    uint4 nc1 = *(const uint4*)&s_cwh[wave][s + 4][4];
    uint4 Q0 = LDKV(no0.x), Q1 = LDKV(no0.y), Q2 = LDKV(no0.z), Q3 = LDKV(no0.w);
    uint4 Q4 = LDKV(no1.x), Q5 = LDKV(no1.y), Q6 = LDKV(no1.z), Q7 = LDKV(no1.w);
    // consume current sample
    __half2 a0 = u2h2(0u), a1 = u2h2(0u), a2 = u2h2(0u), a3 = u2h2(0u);
#define FMA4(WV, PV)                                                          \
    { __half2 w2 = u2h2(WV);                                                  \
      a0 = __hfma2(w2, u2h2((PV).x), a0); a1 = __hfma2(w2, u2h2((PV).y), a1); \
      a2 = __hfma2(w2, u2h2((PV).z), a2); a3 = __hfma2(w2, u2h2((PV).w), a3); }
    FMA4(c0.x, P0) FMA4(c0.y, P1) FMA4(c0.z, P2) FMA4(c0.w, P3)
    FMA4(c1.x, P4) FMA4(c1.y, P5) FMA4(c1.z, P6) FMA4(c1.w, P7)
#undef FMA4
    // k sits in LOW halves, v in HIGH halves of a0..a3
    uint32_t u0 = h22u(a0), u1 = h22u(a1), u2 = h22u(a2), u3 = h22u(a3);
    uint32_t kk01 = (u0 & 0xffffu) | (u1 << 16);
    uint32_t kk23 = (u2 & 0xffffu) | (u3 << 16);
    uint32_t vv01 = (u0 >> 16) | (u1 & 0xffff0000u);
    uint32_t vv23 = (u2 >> 16) | (u3 & 0xffff0000u);
    *(uint2*)&vs_lds[wave][s][m * 2] = make_uint2(vv01, vv23);
    float x = __builtin_amdgcn_fdot2(__builtin_bit_cast(half2_t, kk01), q01,
              __builtin_amdgcn_fdot2(__builtin_bit_cast(half2_t, kk23), q23, 0.f, false), false);
    // 16-lane prefix sum via DPP row_shr; lane15 of each row = group total
#define DPP_ADD(ctrl)                                                            \
    { int t_ = __builtin_amdgcn_update_dpp(0, __float_as_int(x), ctrl, 0xf, 0xf, \
                                           true);                                \
      x += __int_as_float(t_); }
    DPP_ADD(0x111) DPP_ADD(0x112) DPP_ADD(0x114) DPP_ADD(0x118)
#undef DPP_ADD
    if ((lane & 15) == 15) s_dot[wave][s] = x;
    // rotate buffers
    o0 = no0; o1 = no1; c0 = nc0; c1 = nc1;
    P0 = Q0; P1 = Q1; P2 = Q2; P3 = Q3; P4 = Q4; P5 = Q5; P6 = Q6; P7 = Q7;
  }
#undef LDKV

  float logit = (lane < NSAMP) ? s_dot[wave][lane] * 0.125f + pos : -INFINITY;

  // softmax over lanes 0..26
  float mx = logit;
#pragma unroll
  for (int off = 16; off >= 1; off >>= 1) mx = fmaxf(mx, __shfl_xor(mx, off, 64));
  float e = __expf(logit - mx);            // lanes >= 27: exp(-inf) = 0
  float sum = e;
#pragma unroll
  for (int off = 16; off >= 1; off >>= 1) sum += __shfl_xor(sum, off, 64);
  const float wgt = e / sum;

  // pack weight pairs for the PV stage
  uint32_t hw = (uint32_t)f16b(wgt);                       // lanes>=27 -> 0
  uint32_t nw = (uint32_t)__shfl_down((int)hw, 1, 64);     // next lane's weight
  if ((lane & 1) == 0 && lane < 28)
    s_wp[wave][lane >> 1] = hw | (nw << 16);

  // PV: lane = output channel; pair samples (2p, 2p+1) via v_perm + packed fma
  const uint32_t selu = (lane & 1) ? 0x03020706u : 0x01000504u;
  const uint32_t* vbase = &vs_lds[wave][0][lane >> 1];
  __half2 out2 = u2h2(0u);
#pragma unroll
  for (int p = 0; p < 14; ++p) {
    uint32_t d0 = vbase[(2 * p) * 32];
    uint32_t d1 = vbase[(2 * p + 1) * 32];
    uint32_t pk;
    asm("v_perm_b32 %0, %1, %2, %3" : "=v"(pk) : "v"(d0), "v"(d1), "v"(selu));
    out2 = __hfma2(u2h2(s_wp[wave][p]), u2h2(pk), out2);
  }
  float out = __half2float(out2.x) + __half2float(out2.y);
  attb16[(size_t)n * 512 + h * 64 + lane] = f16b(out);
}

// ============ Kernel 4: proj GEMM, 64x64 tiles, BK=64, src-swizzled LDS ============
__global__ __launch_bounds__(256) void k_proj(const ushort_t* __restrict__ Ah,
                                              const ushort_t* __restrict__ Bth,
                                              const float* __restrict__ bias,
                                              float* __restrict__ out) {
  __shared__ __align__(16) ushort_t As[64 * 64];
  __shared__ __align__(16) ushort_t Bs[64 * 64];
  const int tid = threadIdx.x;
  const int wave = tid >> 6, lane = tid & 63;
  const int wr = wave >> 1, wc = wave & 1;
  const int m15 = lane & 15, quad = lane >> 4;
  const int bm = blockIdx.x, bn = blockIdx.y;
  floatx4 acc[2][2];
#pragma unroll
  for (int i = 0; i < 2; i++)
#pragma unroll
    for (int j = 0; j < 2; j++) acc[i][j] = {0.f, 0.f, 0.f, 0.f};

  for (int k0 = 0; k0 < 512; k0 += 64) {
#pragma unroll
    for (int it = 0; it < 2; it++) {
      int id = it * 256 + tid, row = id >> 3, ch = id & 7;
      int sch = ch ^ (row & 7);
      gl2lds16(&Ah[(size_t)(bm * 64 + row) * 512 + k0 + sch * 8],  &As[row * 64 + ch * 8]);
      gl2lds16(&Bth[(size_t)(bn * 64 + row) * 512 + k0 + sch * 8], &Bs[row * 64 + ch * 8]);
    }
    __syncthreads();
#pragma unroll
    for (int k4 = 0; k4 < 8; k4 += 4) {    // kk in {0,32}
      half8 af[2], bf[2];
#pragma unroll
      for (int i = 0; i < 2; i++) {
        int row = wr * 32 + i * 16 + m15;
        af[i] = *(const half8*)&As[row * 64 + ((quad + k4) ^ (row & 7)) * 8];
      }
#pragma unroll
      for (int j = 0; j < 2; j++) {
        int row = wc * 32 + j * 16 + m15;
        bf[j] = *(const half8*)&Bs[row * 64 + ((quad + k4) ^ (row & 7)) * 8];
      }
#pragma unroll
      for (int i = 0; i < 2; i++)
#pragma unroll
        for (int j = 0; j < 2; j++)
          acc[i][j] = __builtin_amdgcn_mfma_f32_16x16x32_f16(af[i], bf[j], acc[i][j], 0, 0, 0);
    }
    __syncthreads();
  }

#pragma unroll
  for (int i = 0; i < 2; i++)
#pragma unroll
    for (int j = 0; j < 2; j++) {
      int col = bn * 64 + wc * 32 + j * 16 + m15;
      float b = bias[col];
#pragma unroll
      for (int r = 0; r < 4; r++) {
        int row = bm * 64 + wr * 32 + i * 16 + quad * 4 + r;
        out[(size_t)row * 512 + col] = acc[i][j][r] + b;
      }
    }
}

extern "C" void kernel_launch(void* const* d_in, const int* in_sizes, int n_in,
                              void* d_out, int out_size, void* d_ws, size_t ws_size,
                              hipStream_t stream) {
  const float* x      = (const float*)d_in[0];
  const float* w_qkv  = (const float*)d_in[1];
  const float* w_proj = (const float*)d_in[2];
  const float* b_proj = (const float*)d_in[3];
  const float* w_off  = (const float*)d_in[4];
  const float* rel_d  = (const float*)d_in[5];
  const float* rel_h  = (const float*)d_in[6];
  const float* rel_w  = (const float*)d_in[7];

  char* ws = (char*)d_ws;
  uint32_t* kvb    = (uint32_t*)ws; ws += (size_t)NH * NTOK * 64 * 4;
  float*    ob     = (float*)ws;    ws += (size_t)NH * NTOK * 81 * 4;
  float*    Pb     = (float*)ws;    ws += (size_t)NH * NTOK * 126 * 4;
  ushort_t* attb16 = (ushort_t*)ws; ws += (size_t)NTOK * CDIM * 2;
  ushort_t* xh     = (ushort_t*)ws; ws += (size_t)NTOK * CDIM * 2;
  ushort_t* wqh    = (ushort_t*)ws; ws += (size_t)3 * CDIM * CDIM * 2;
  ushort_t* wph    = (ushort_t*)ws; ws += (size_t)CDIM * CDIM * 2;
  ushort_t* qh16   = (ushort_t*)ws; ws += (size_t)NH * NTOK * 64 * 2;
  ushort_t* w_offh = (ushort_t*)ws; ws += (size_t)128 * 64 * 2;
  ushort_t* relh   = (ushort_t*)ws; ws += (size_t)128 * 64 * 2;
  float*    out    = (float*)d_out;

  k_cvt <<<dim3(3088), dim3(256), 0, stream>>>(x, w_qkv, w_proj, w_off, rel_d, rel_h,
                                               rel_w, xh, wqh, wph, w_offh, relh);
  k_qkv <<<dim3(64, 12), dim3(256), 0, stream>>>(xh, wqh, qh16, kvb);
  k_aux <<<dim3(32, 16), dim3(256), 0, stream>>>(xh, qh16, w_offh, relh, ob, Pb);
  k_attn<<<dim3(8192),   dim3(256), 0, stream>>>(qh16, kvb, ob, Pb, attb16);
  k_proj<<<dim3(64, 8),  dim3(256), 0, stream>>>(attb16, wph, b_proj, out);
}